// Round 3
// baseline (689.296 us; speedup 1.0000x reference)
//
#include <hip/hip_runtime.h>

#define B_DIM 64
#define S_DIM 784
#define T_DIM 500
#define N_DIM 1024
#define TP    522
#define KS    21
#define THETA 80
#define NCHUNK 8
#define CH    66
#define LISTCAP 128
#define DUMP_ENTRY (S_DIM << 10)   // pad entries point at the all-63 row (s=784)

// ---- K1: wt9[s][n] = w ? 9*(w-1) : 63; extra row s=784 all-63 (dump target for
//          list padding). Also zero the per-(b,t) list counters.
__global__ void k_prep(const int* __restrict__ w, unsigned char* __restrict__ wt9,
                       unsigned* __restrict__ gcnt) {
  unsigned idx = blockIdx.x * 256 + threadIdx.x;
  if (idx < (S_DIM + 1) * N_DIM) {
    unsigned s = idx >> 10, n = idx & 1023;
    unsigned char v = 63;
    if (s < S_DIM) {
      int wv = w[n * S_DIM + s];
      v = wv ? (unsigned char)(9 * (wv - 1)) : (unsigned char)63;
    }
    wt9[idx] = v;
  }
  if (idx < B_DIM * T_DIM) gcnt[idx] = 0;
}

// ---- K2: build per-(b,t) spike lists (float4 reads; order irrelevant: sums commute)
__global__ void k_lists(const float4* __restrict__ x4, unsigned* __restrict__ gcnt,
                        unsigned short* __restrict__ glist) {
  unsigned idx = blockIdx.x * 256 + threadIdx.x;  // over B*S*(T/4)
  if (idx >= B_DIM * S_DIM * (T_DIM / 4)) return;
  float4 v = x4[idx];
  if (v.x == 0.0f && v.y == 0.0f && v.z == 0.0f && v.w == 0.0f) return;
  unsigned tq = idx % (T_DIM / 4);
  unsigned bs = idx / (T_DIM / 4);       // b*S + s
  unsigned s = bs % S_DIM;
  unsigned b = bs / S_DIM;
  unsigned cell = b * T_DIM + tq * 4;
  float f[4] = {v.x, v.y, v.z, v.w};
  #pragma unroll
  for (int k = 0; k < 4; ++k) {
    if (f[k] != 0.0f) {
      unsigned pos = atomicAdd(&gcnt[cell + k], 1u);
      if (pos < LISTCAP) glist[(cell + k) * LISTCAP + pos] = (unsigned short)s;
    }
  }
}

// ---- K3: barrier-free fused sparse conv + argmax; modulo-22 register ring
//          (no shifts), 4-wide spike processing via ds_read_b128.
__global__ void __launch_bounds__(1024)
k_main(const unsigned char* __restrict__ wt9,
       const unsigned* __restrict__ gcnt,
       const unsigned short* __restrict__ glist,
       unsigned* __restrict__ red) {
  __shared__ unsigned s_list[87][LISTCAP];   // pre-shifted s<<10, padded to x4
  __shared__ int s_cnt[87];                  // counts rounded up to multiple of 4
  __shared__ unsigned smax[CH];

  const int tid = threadIdx.x;
  const int b = blockIdx.y;
  const int lo = blockIdx.x * CH;
  const int hi = min(TP - 1, lo + CH - 1);
  const int t0 = max(0, lo - KS);
  const int n_emit = hi - lo + 1;
  const int nt_in = min(hi, T_DIM - 1) - t0 + 1;

  // ---- prologue: stage lists (u16 -> u32 pre-shifted), counts, smax
  const unsigned cell0 = (unsigned)b * T_DIM + (unsigned)t0;
  for (int i = tid; i < nt_in; i += 1024) {
    int c = min((int)gcnt[cell0 + i], LISTCAP);
    s_cnt[i] = (c + 3) & ~3;
  }
  {
    const unsigned short* src = glist + (size_t)cell0 * LISTCAP;
    const int ne = nt_in * LISTCAP;
    for (int i = tid; i < ne; i += 1024)
      s_list[0][i] = (unsigned)src[i] << 10;
  }
  for (int i = tid; i < n_emit; i += 1024) smax[i] = 0u;
  __syncthreads();
  // pad each list's tail slots [cnt, cnt4) with the dump entry
  if (tid < nt_in) {
    int c = min((int)gcnt[cell0 + tid], LISTCAP);
    int c4 = (c + 3) & ~3;
    for (int j = c; j < c4; ++j) s_list[tid][j] = (unsigned)DUMP_ENTRY;
  }
  __syncthreads();

  unsigned ring[22];
  #pragma unroll
  for (int i = 0; i < 22; ++i) ring[i] = 0;

  const unsigned invn = (unsigned)(1023 - tid);

  for (int tb = t0; tb <= hi; tb += 22) {
    #pragma unroll
    for (int k = 0; k < 22; ++k) {
      const int t = tb + k;
      if (t > hi) break;

      // pot[t] is complete in ring[(t-tb+...)%22] == ring[k'] with period-22 mapping
      if (t >= lo) {
        unsigned key = (ring[k] << 10) | invn;
        #pragma unroll
        for (int off = 32; off > 0; off >>= 1) {
          unsigned o = __shfl_xor(key, off, 64);
          key = key > o ? key : o;
        }
        if ((tid & 63) == 0) atomicMax(&smax[t - lo], key);
      }
      ring[k] = 0;  // becomes the far-future slot t+22

      if (t < T_DIM) {
        const int li = t - t0;
        const int cnt4 = __builtin_amdgcn_readfirstlane(s_cnt[li]);
        const uint4* lp4 = (const uint4*)&s_list[li][0];
        unsigned long long c0 = 0, c1 = 0, c2 = 0, c3 = 0;
        for (int i = 0; i < cnt4; i += 4) {
          uint4 e = lp4[i >> 2];                 // ds_read_b128, broadcast
          c0 += 1ull << wt9[e.x + tid];
          c1 += 1ull << wt9[e.y + tid];
          c2 += 1ull << wt9[e.z + tid];
          c3 += 1ull << wt9[e.w + tid];
        }
        const unsigned long long c = (c0 + c1) + (c2 + c3);

        const int c1_ = (int)(c & 511), c2_ = (int)((c >> 9) & 511),
                  c3_ = (int)((c >> 18) & 511), c4_ = (int)((c >> 27) & 511),
                  c5_ = (int)((c >> 36) & 511), c6_ = (int)((c >> 45) & 511),
                  c7_ = (int)((c >> 54) & 511);
        // response application as running-delta adds (verified exact in R2)
        const int S7 = c7_, S6 = S7 + c6_, S5 = S6 + c5_, S4 = S5 + c4_,
                  S3 = S4 + c3_, S2 = S3 + c2_, S1 = S2 + c1_;
        const int O1 = c1_, O3 = O1 + c3_, O5 = O3 + c5_, O7 = O5 + c7_;
        const int E2 = c2_, E4 = E2 + c4_, E6 = E4 + c6_;
        const int O31 = O3 - O1, O51 = O5 - O1, O71 = O7 - O1,
                  O73 = O7 - O3, O75 = O7 - O5;
        const int E62 = E6 - E2, E64 = E6 - E4;
        int acc = S1;        ring[(k + 1)  % 22] += acc;
        acc += S2;           ring[(k + 2)  % 22] += acc;
        acc += S3 - O1;      ring[(k + 3)  % 22] += acc;
        acc += S4 - E2;      ring[(k + 4)  % 22] += acc;
        acc += S5 - O31;     ring[(k + 5)  % 22] += acc;
        acc += S6 - E4;      ring[(k + 6)  % 22] += acc;
        acc += S7 - O51;     ring[(k + 7)  % 22] += acc;
        acc -= E62;          ring[(k + 8)  % 22] += acc;
        acc -= O71;          ring[(k + 9)  % 22] += acc;
        acc -= E62;          ring[(k + 10) % 22] += acc;
        acc -= O73;          ring[(k + 11) % 22] += acc;
        acc -= E62;          ring[(k + 12) % 22] += acc;
        acc -= O73;          ring[(k + 13) % 22] += acc;
        acc -= E64;          ring[(k + 14) % 22] += acc;
        acc -= O73;          ring[(k + 15) % 22] += acc;
        acc -= E64;          ring[(k + 16) % 22] += acc;
        acc -= O75;          ring[(k + 17) % 22] += acc;
        acc -= E64;          ring[(k + 18) % 22] += acc;
        acc -= O75;          ring[(k + 19) % 22] += acc;
                             ring[(k + 20) % 22] += acc;
        acc -= O75;          ring[(k + 21) % 22] += acc;
      }
    }
  }

  __syncthreads();
  for (int i = tid; i < n_emit; i += 1024)
    red[(unsigned)b * TP + (unsigned)(lo + i)] = smax[i];
}

// ---- K4: winner-take-all dep scan; 6-wide load batching to hide L2 latency
__global__ void k_scan(const unsigned* __restrict__ red, int* __restrict__ out) {
  int b = threadIdx.x;
  if (b >= B_DIM) return;
  int dep = 0;
  for (int base = 0; base < TP; base += 6) {   // 522 = 87*6
    unsigned buf[6];
    #pragma unroll
    for (int k = 0; k < 6; ++k) buf[k] = red[b * TP + base + k];
    #pragma unroll
    for (int k = 0; k < 6; ++k) {
      unsigned key = buf[k];
      int val = (int)(key >> 10);
      bool cond = (val > THETA) && (dep == 0);
      if (cond) {
        int idx = 1023 - (int)(key & 1023);
        out[(b * N_DIM + idx) * TP + base + k] = 1;
        dep = 22;  // FODEP+1
      }
      dep = max(0, dep - 1);
    }
  }
}

extern "C" void kernel_launch(void* const* d_in, const int* in_sizes, int n_in,
                              void* d_out, int out_size, void* d_ws, size_t ws_size,
                              hipStream_t stream) {
  const float* x = (const float*)d_in[0];
  const int* wgt = (const int*)d_in[1];
  int* out = (int*)d_out;

  // workspace layout (total ~9.26 MB)
  unsigned char* wt9    = (unsigned char*)d_ws;                           // 803,840 B (785 rows)
  unsigned* gcnt        = (unsigned*)((char*)d_ws + 803840);              // 128,000 B
  unsigned short* glist = (unsigned short*)((char*)d_ws + 931840);        // 8,192,000 B
  unsigned* red         = (unsigned*)((char*)d_ws + 9123840);             // 133,632 B

  hipMemsetAsync(d_out, 0, (size_t)out_size * sizeof(int), stream);
  k_prep<<<((S_DIM + 1) * N_DIM + 255) / 256, 256, 0, stream>>>(wgt, wt9, gcnt);
  k_lists<<<(B_DIM * S_DIM * (T_DIM / 4) + 255) / 256, 256, 0, stream>>>(
      (const float4*)x, gcnt, glist);
  k_main<<<dim3(NCHUNK, B_DIM), 1024, 0, stream>>>(wt9, gcnt, glist, red);
  k_scan<<<1, 64, 0, stream>>>(red, out);
}